// Round 1
// baseline (589.710 us; speedup 1.0000x reference)
//
#include <hip/hip_runtime.h>
#include <cstdint>
#include <cstddef>

// ---------------------------------------------------------------------------
// 2-layer GCN: h1 = x@W1; s = softmax(A_norm@h1 + b1); out = A_norm@(s@W2) + b2
// A_norm has self-loops, sym-normalized by in-degree (dst-count + 1).
// Device pipeline:
//   1) deg histogram (int atomics)   2) single-block exclusive scan -> row_start,
//      fused dinv = rsqrt(deg+1)     3) cursor copy  4) CSR fill (int atomics)
//   5) GEMM1 (fp32, W fully in LDS)  6) per-node gather-aggregate + bias +
//      self-loop + fused softmax     7) GEMM2       8) per-node aggregate -> out
// No float atomics anywhere.
// ---------------------------------------------------------------------------

__device__ __forceinline__ void fma4(float4& a, float s, const float4& b) {
  a.x = fmaf(s, b.x, a.x);
  a.y = fmaf(s, b.y, a.y);
  a.z = fmaf(s, b.z, a.z);
  a.w = fmaf(s, b.w, a.w);
}

__global__ __launch_bounds__(256) void count_deg(const int* __restrict__ dst,
                                                 int* __restrict__ deg, int E) {
  int e = blockIdx.x * 256 + threadIdx.x;
  if (e < E) atomicAdd(&deg[dst[e]], 1);
}

// Single-block exclusive scan over deg[0..n-1] -> row_start[0..n], plus
// dinv[i] = rsqrt(deg[i] + 1)  (the +1 is the self-loop).
__global__ __launch_bounds__(1024) void scan_deg(const int* __restrict__ deg,
                                                 int* __restrict__ row_start,
                                                 float* __restrict__ dinv, int n) {
  __shared__ int wsum[16];
  const int tid = threadIdx.x;
  const int lane = tid & 63;
  const int wid = tid >> 6;
  int carry = 0;
  for (int base = 0; base < n; base += 1024) {
    int i = base + tid;
    int v = (i < n) ? deg[i] : 0;
    int x = v;
#pragma unroll
    for (int d = 1; d < 64; d <<= 1) {
      int y = __shfl_up(x, d);
      if (lane >= d) x += y;
    }
    if (lane == 63) wsum[wid] = x;
    __syncthreads();
    if (wid == 0) {
      int w = (lane < 16) ? wsum[lane] : 0;
#pragma unroll
      for (int d = 1; d < 16; d <<= 1) {
        int y = __shfl_up(w, d);
        if (lane >= d) w += y;
      }
      if (lane < 16) wsum[lane] = w;
    }
    __syncthreads();
    int boff = (wid > 0) ? wsum[wid - 1] : 0;
    int incl = carry + boff + x;
    if (i < n) {
      row_start[i] = incl - v;          // exclusive prefix
      dinv[i] = rsqrtf((float)v + 1.0f);
      if (i == n - 1) row_start[n] = incl;
    }
    carry += wsum[15];
    __syncthreads();  // protect wsum for next chunk
  }
}

__global__ __launch_bounds__(256) void copy_i32(const int* __restrict__ a,
                                                int* __restrict__ b, int n) {
  int i = blockIdx.x * 256 + threadIdx.x;
  if (i < n) b[i] = a[i];
}

__global__ __launch_bounds__(256) void fill_csr(const int* __restrict__ src,
                                                const int* __restrict__ dst,
                                                int* __restrict__ cursor,
                                                int* __restrict__ csr_src, int E) {
  int e = blockIdx.x * 256 + threadIdx.x;
  if (e < E) {
    int d = dst[e];
    int p = atomicAdd(&cursor[d], 1);
    csr_src[p] = src[e];
  }
}

// H[N,M] = X[N,128] @ W[128,M].  W fully staged in LDS (k-major), X tile
// row-major in LDS. 256 threads, micro-tile 4 rows x 4 cols per thread.
template <int M>
__global__ __launch_bounds__(256) void gemm_k128(const float* __restrict__ X,
                                                 const float* __restrict__ W,
                                                 float* __restrict__ H, int N) {
  constexpr int CT = M / 4;    // col-thread groups: 32 (M=128) / 16 (M=64)
  constexpr int RT = 256 / CT; // 8 / 16
  constexpr int BM = RT * 4;   // 32 / 64 rows per block
  __shared__ float Ws[128 * M];   // Ws[k*M + c]
  __shared__ float Xs[BM * 128];  // Xs[r*128 + k]
  const int tid = threadIdx.x;
  const int r0 = blockIdx.x * BM;

  {
    const float4* Wv = (const float4*)W;
    float4* Wsv = (float4*)Ws;
    constexpr int TOT = 128 * M / 4;
#pragma unroll
    for (int i = tid; i < TOT; i += 256) Wsv[i] = Wv[i];
  }
  {
    const float4* Xv = (const float4*)X;
    float4* Xsv = (float4*)Xs;
    constexpr int TOT = BM * 32;
#pragma unroll
    for (int i = tid; i < TOT; i += 256) {
      int r = r0 + i / 32;
      int c = i % 32;
      int rr = (r < N) ? r : (N - 1);  // clamp: safe OOB guard for tail block
      Xsv[i] = Xv[(size_t)rr * 32 + c];
    }
  }
  __syncthreads();

  const int ct = tid % CT;
  const int rt = tid / CT;
  float4 acc[4];
#pragma unroll
  for (int i = 0; i < 4; ++i) acc[i] = make_float4(0.f, 0.f, 0.f, 0.f);

  const float* xb = &Xs[(4 * rt) * 128];
  const float* wb = &Ws[4 * ct];
#pragma unroll 4
  for (int k = 0; k < 128; k += 4) {
    float4 xq[4];
#pragma unroll
    for (int i = 0; i < 4; ++i) xq[i] = *(const float4*)&xb[i * 128 + k];
    float4 w0 = *(const float4*)&wb[(k + 0) * M];
    float4 w1 = *(const float4*)&wb[(k + 1) * M];
    float4 w2 = *(const float4*)&wb[(k + 2) * M];
    float4 w3 = *(const float4*)&wb[(k + 3) * M];
#pragma unroll
    for (int i = 0; i < 4; ++i) {
      fma4(acc[i], xq[i].x, w0);
      fma4(acc[i], xq[i].y, w1);
      fma4(acc[i], xq[i].z, w2);
      fma4(acc[i], xq[i].w, w3);
    }
  }

#pragma unroll
  for (int i = 0; i < 4; ++i) {
    int r = r0 + 4 * rt + i;
    if (r < N) *(float4*)&H[(size_t)r * M + 4 * ct] = acc[i];
  }
}

// Per-node gather-aggregate: out[node] = bias + h[node]*dinv^2 + sum_in
// h[src]*dinv[src]*dinv[node].  F=128: 32 lanes/node; F=64: 16 lanes/node.
// SM: fused row-softmax across the group's F values.
template <int F, bool SM>
__global__ __launch_bounds__(256) void aggregate(const float* __restrict__ h,
                                                 const int* __restrict__ row_start,
                                                 const int* __restrict__ csr_src,
                                                 const float* __restrict__ dinv,
                                                 const float* __restrict__ bias,
                                                 float* __restrict__ out, int n) {
  constexpr int LPG = F / 4;      // lanes per group: 32 / 16
  constexpr int GPB = 256 / LPG;  // groups per block: 8 / 16
  const int node = blockIdx.x * GPB + (int)(threadIdx.x / LPG);
  const int lane = threadIdx.x % LPG;
  if (node >= n) return;

  const float di = dinv[node];
  const float4* hv = (const float4*)h;
  float4 b = ((const float4*)bias)[lane];
  float4 sv = hv[(size_t)node * LPG + lane];
  const float sn = di * di;
  float4 acc;
  acc.x = fmaf(sv.x, sn, b.x);
  acc.y = fmaf(sv.y, sn, b.y);
  acc.z = fmaf(sv.z, sn, b.z);
  acc.w = fmaf(sv.w, sn, b.w);

  const int e0 = row_start[node];
  const int e1 = row_start[node + 1];
  for (int e = e0; e < e1; ++e) {
    int s = csr_src[e];
    float nrm = dinv[s] * di;
    float4 v = hv[(size_t)s * LPG + lane];
    fma4(acc, nrm, v);
  }

  if constexpr (SM) {
    float m = fmaxf(fmaxf(acc.x, acc.y), fmaxf(acc.z, acc.w));
#pragma unroll
    for (int off = LPG / 2; off >= 1; off >>= 1) m = fmaxf(m, __shfl_xor(m, off));
    float4 ex;
    ex.x = __expf(acc.x - m);
    ex.y = __expf(acc.y - m);
    ex.z = __expf(acc.z - m);
    ex.w = __expf(acc.w - m);
    float ssum = ex.x + ex.y + ex.z + ex.w;
#pragma unroll
    for (int off = LPG / 2; off >= 1; off >>= 1) ssum += __shfl_xor(ssum, off);
    float r = 1.0f / ssum;
    acc.x = ex.x * r;
    acc.y = ex.y * r;
    acc.z = ex.z * r;
    acc.w = ex.w * r;
  }

  ((float4*)out)[(size_t)node * LPG + lane] = acc;
}

extern "C" void kernel_launch(void* const* d_in, const int* in_sizes, int n_in,
                              void* d_out, int out_size, void* d_ws, size_t ws_size,
                              hipStream_t stream) {
  const float* x  = (const float*)d_in[0];
  const float* W1 = (const float*)d_in[1];
  const float* b1 = (const float*)d_in[2];
  const float* W2 = (const float*)d_in[3];
  const float* b2 = (const float*)d_in[4];
  const int*   ei = (const int*)d_in[5];

  const int N = in_sizes[0] / 128;
  const int E = in_sizes[5] / 2;
  const int* srcp = ei;
  const int* dstp = ei + E;

  auto align256 = [](size_t v) { return (v + 255) & ~(size_t)255; };
  char* ws = (char*)d_ws;
  size_t o_dinv = 0;
  size_t o_rs   = align256(o_dinv + (size_t)N * 4);
  size_t o_cur  = align256(o_rs + (size_t)(N + 1) * 4);
  size_t o_csr  = align256(o_cur + (size_t)N * 4);
  size_t o_h1   = align256(o_csr + (size_t)E * 4);
  size_t o_s    = align256(o_h1 + (size_t)N * 128 * 4);

  float* dinv     = (float*)(ws + o_dinv);
  int*   rowstart = (int*)(ws + o_rs);
  int*   cursor   = (int*)(ws + o_cur);
  int*   csr_src  = (int*)(ws + o_csr);
  float* h1       = (float*)(ws + o_h1);  // [N,128]; reused as h2 [N,64]
  float* sbuf     = (float*)(ws + o_s);   // [N,128] softmax output

  // 1) degree histogram (cursor doubles as deg buffer)
  hipMemsetAsync(cursor, 0, (size_t)N * 4, stream);
  count_deg<<<(E + 255) / 256, 256, 0, stream>>>(dstp, cursor, E);
  // 2) scan -> row_start, fused dinv
  scan_deg<<<1, 1024, 0, stream>>>(cursor, rowstart, dinv, N);
  // 3) cursor = row_start
  copy_i32<<<(N + 255) / 256, 256, 0, stream>>>(rowstart, cursor, N);
  // 4) CSR fill
  fill_csr<<<(E + 255) / 256, 256, 0, stream>>>(srcp, dstp, cursor, csr_src, E);
  // 5) h1 = x @ W1
  gemm_k128<128><<<(N + 31) / 32, 256, 0, stream>>>(x, W1, h1, N);
  // 6) s = softmax(aggregate(h1) + b1)
  aggregate<128, true><<<(N + 7) / 8, 256, 0, stream>>>(h1, rowstart, csr_src,
                                                        dinv, b1, sbuf, N);
  // 7) h2 = s @ W2  (into h1 buffer)
  gemm_k128<64><<<(N + 63) / 64, 256, 0, stream>>>(sbuf, W2, h1, N);
  // 8) out = aggregate(h2) + b2
  aggregate<64, false><<<(N + 15) / 16, 256, 0, stream>>>(h1, rowstart, csr_src,
                                                          dinv, b2, (float*)d_out, N);
}

// Round 2
// 483.657 us; speedup vs baseline: 1.2193x; 1.2193x over previous
//
#include <hip/hip_runtime.h>
#include <hip/hip_fp16.h>
#include <cstdint>
#include <cstddef>

// ---------------------------------------------------------------------------
// 2-layer GCN: h1 = x@W1; s = softmax(A_norm@h1 + b1); out = A_norm@(s@W2) + b2
// CSR build via two-level counting sort (buckets of 128 dst nodes) so all HBM
// writes are coalesced; degrees/row_start/dinv fall out of the bucket pass.
// Aggregation factored as out = di*(sum dinv[src]*h[src] + di*h[node]) + b
// with per-edge w = dinv[src] precomputed (removes dependent load in loop).
// Layer-2 intermediate h2 stored fp16 to halve gather bytes.
// ---------------------------------------------------------------------------

#define BSHIFT 7              // 128 nodes per bucket
#define BPAD 16               // bucket counter padding (64B) to spread L2 banks
#define CAP 4096              // LDS reorder buffer (mean bucket ~2048 edges)

__device__ __forceinline__ void fma4(float4& a, float s, const float4& b) {
  a.x = fmaf(s, b.x, a.x);
  a.y = fmaf(s, b.y, a.y);
  a.z = fmaf(s, b.z, a.z);
  a.w = fmaf(s, b.w, a.w);
}

__global__ __launch_bounds__(256) void bucket_count(const int* __restrict__ dst,
                                                    int* __restrict__ bcnt, int E) {
  int e = blockIdx.x * 256 + threadIdx.x;
  if (e < E) atomicAdd(&bcnt[(dst[e] >> BSHIFT) * BPAD], 1);
}

// Single block: exclusive scan over nb (<=1024) bucket counts -> bstart,
// preload cursors, and write row_start[n] = E.
__global__ __launch_bounds__(1024) void bucket_scan(const int* __restrict__ bcnt,
                                                    int* __restrict__ bstart,
                                                    int* __restrict__ bcur,
                                                    int* __restrict__ row_start,
                                                    int nb, int n, int E) {
  __shared__ int wsum[16];
  const int tid = threadIdx.x;
  const int lane = tid & 63;
  const int wid = tid >> 6;
  int v = (tid < nb) ? bcnt[tid * BPAD] : 0;
  int x = v;
#pragma unroll
  for (int d = 1; d < 64; d <<= 1) {
    int y = __shfl_up(x, d);
    if (lane >= d) x += y;
  }
  if (lane == 63) wsum[wid] = x;
  __syncthreads();
  if (wid == 0) {
    int w = (lane < 16) ? wsum[lane] : 0;
#pragma unroll
    for (int d = 1; d < 16; d <<= 1) {
      int y = __shfl_up(w, d);
      if (lane >= d) w += y;
    }
    if (lane < 16) wsum[lane] = w;
  }
  __syncthreads();
  int boff = (wid > 0) ? wsum[wid - 1] : 0;
  int incl = boff + x;
  if (tid < nb) {
    int excl = incl - v;
    bstart[tid] = excl;
    bcur[tid * BPAD] = excl;
    if (tid == nb - 1) bstart[nb] = incl;
  }
  if (tid == 0) row_start[n] = E;
}

__global__ __launch_bounds__(256) void bucket_scatter(const int* __restrict__ src,
                                                      const int* __restrict__ dst,
                                                      int* __restrict__ bcur,
                                                      unsigned* __restrict__ staging,
                                                      int E) {
  int e = blockIdx.x * 256 + threadIdx.x;
  if (e < E) {
    int d = dst[e];
    int p = atomicAdd(&bcur[(d >> BSHIFT) * BPAD], 1);
    staging[p] = ((unsigned)(d & ((1 << BSHIFT) - 1)) << 25) | (unsigned)src[e];
  }
}

// One block per bucket: LDS histogram over 128 local nodes -> local scan ->
// row_start + dinv (coalesced) -> LDS reorder -> coalesced csr_src write.
__global__ __launch_bounds__(256) void bucket_finalize(const unsigned* __restrict__ staging,
                                                       const int* __restrict__ bstart,
                                                       int* __restrict__ csr_src,
                                                       int* __restrict__ row_start,
                                                       float* __restrict__ dinv, int n) {
  __shared__ int lcnt[128];
  __shared__ int lcur[128];
  __shared__ int w0tot;
  __shared__ int lbuf[CAP];
  const int b = blockIdx.x;
  const int tid = threadIdx.x;
  const int n0 = b << BSHIFT;
  const int s0 = bstart[b];
  const int cnt = bstart[b + 1] - s0;

  if (tid < 128) lcnt[tid] = 0;
  __syncthreads();
  for (int i = tid; i < cnt; i += 256) {
    unsigned p = staging[s0 + i];
    atomicAdd(&lcnt[p >> 25], 1);
  }
  __syncthreads();

  const int lane = tid & 63;
  int v = 0, x = 0;
  if (tid < 128) {
    v = lcnt[tid];
    x = v;
#pragma unroll
    for (int d = 1; d < 64; d <<= 1) {
      int y = __shfl_up(x, d);
      if (lane >= d) x += y;
    }
  }
  if (tid == 63) w0tot = x;
  __syncthreads();
  if (tid < 128) {
    int excl = x - v + ((tid >= 64) ? w0tot : 0);
    lcur[tid] = excl;
    int node = n0 + tid;
    if (node < n) {
      row_start[node] = s0 + excl;
      dinv[node] = rsqrtf((float)v + 1.0f);
    }
  }
  __syncthreads();

  for (int i = tid; i < cnt; i += 256) {
    unsigned p = staging[s0 + i];
    int dl = p >> 25;
    int src = (int)(p & 0x1FFFFFFu);
    int pos = atomicAdd(&lcur[dl], 1);
    if (pos < CAP) lbuf[pos] = src;
    else csr_src[s0 + pos] = src;  // overflow fallback (statistically never)
  }
  __syncthreads();
  const int lim = cnt < CAP ? cnt : CAP;
  for (int i = tid; i < lim; i += 256) csr_src[s0 + i] = lbuf[i];
}

__global__ __launch_bounds__(256) void make_w(const int* __restrict__ csr_src,
                                              const float* __restrict__ dinv,
                                              float* __restrict__ w, int E) {
  int e = blockIdx.x * 256 + threadIdx.x;
  if (e < E) w[e] = dinv[csr_src[e]];
}

// H[N,M] = X[N,128] @ W[128,M].  W fully staged in LDS (k-major), X tile
// row-major in LDS. 256 threads, micro-tile 4 rows x 4 cols per thread.
template <int M, bool HOUT>
__global__ __launch_bounds__(256) void gemm_k128(const float* __restrict__ X,
                                                 const float* __restrict__ W,
                                                 void* __restrict__ Hout, int N) {
  constexpr int CT = M / 4;
  constexpr int RT = 256 / CT;
  constexpr int BM = RT * 4;
  __shared__ float Ws[128 * M];
  __shared__ float Xs[BM * 128];
  const int tid = threadIdx.x;
  const int r0 = blockIdx.x * BM;

  {
    const float4* Wv = (const float4*)W;
    float4* Wsv = (float4*)Ws;
    constexpr int TOT = 128 * M / 4;
#pragma unroll
    for (int i = tid; i < TOT; i += 256) Wsv[i] = Wv[i];
  }
  {
    const float4* Xv = (const float4*)X;
    float4* Xsv = (float4*)Xs;
    constexpr int TOT = BM * 32;
#pragma unroll
    for (int i = tid; i < TOT; i += 256) {
      int r = r0 + i / 32;
      int c = i % 32;
      int rr = (r < N) ? r : (N - 1);
      Xsv[i] = Xv[(size_t)rr * 32 + c];
    }
  }
  __syncthreads();

  const int ct = tid % CT;
  const int rt = tid / CT;
  float4 acc[4];
#pragma unroll
  for (int i = 0; i < 4; ++i) acc[i] = make_float4(0.f, 0.f, 0.f, 0.f);

  const float* xb = &Xs[(4 * rt) * 128];
  const float* wb = &Ws[4 * ct];
#pragma unroll 4
  for (int k = 0; k < 128; k += 4) {
    float4 xq[4];
#pragma unroll
    for (int i = 0; i < 4; ++i) xq[i] = *(const float4*)&xb[i * 128 + k];
    float4 w0 = *(const float4*)&wb[(k + 0) * M];
    float4 w1 = *(const float4*)&wb[(k + 1) * M];
    float4 w2 = *(const float4*)&wb[(k + 2) * M];
    float4 w3 = *(const float4*)&wb[(k + 3) * M];
#pragma unroll
    for (int i = 0; i < 4; ++i) {
      fma4(acc[i], xq[i].x, w0);
      fma4(acc[i], xq[i].y, w1);
      fma4(acc[i], xq[i].z, w2);
      fma4(acc[i], xq[i].w, w3);
    }
  }

#pragma unroll
  for (int i = 0; i < 4; ++i) {
    int r = r0 + 4 * rt + i;
    if (r < N) {
      if constexpr (HOUT) {
        __half* H = (__half*)Hout;
        union { struct { __half2 a, b; } h; uint2 u; } cv;
        cv.h.a = __floats2half2_rn(acc[i].x, acc[i].y);
        cv.h.b = __floats2half2_rn(acc[i].z, acc[i].w);
        *(uint2*)&H[(size_t)r * M + 4 * ct] = cv.u;
      } else {
        float* H = (float*)Hout;
        *(float4*)&H[(size_t)r * M + 4 * ct] = acc[i];
      }
    }
  }
}

// out[node] = di*( sum_e w[e]*h[src_e] + di*h[node] ) + bias, then optional
// row-softmax. F=128: 32 lanes/node; F=64: 16 lanes/node.
template <int F, bool SM, bool HALFIN>
__global__ __launch_bounds__(256) void aggregate(const void* __restrict__ hp,
                                                 const int* __restrict__ row_start,
                                                 const int* __restrict__ csr_src,
                                                 const float* __restrict__ csr_w,
                                                 const float* __restrict__ dinv,
                                                 const float* __restrict__ bias,
                                                 float* __restrict__ out, int n) {
  constexpr int LPG = F / 4;
  constexpr int GPB = 256 / LPG;
  const int node = blockIdx.x * GPB + (int)(threadIdx.x / LPG);
  const int lane = threadIdx.x % LPG;
  if (node >= n) return;

  const float di = dinv[node];

  auto loadrow = [&](int r) -> float4 {
    if constexpr (HALFIN) {
      const __half* p = (const __half*)hp + (size_t)r * F + lane * 4;
      uint2 u = *(const uint2*)p;
      __half2 h0 = *(__half2*)&u.x;
      __half2 h1 = *(__half2*)&u.y;
      float2 f0 = __half22float2(h0), f1 = __half22float2(h1);
      return make_float4(f0.x, f0.y, f1.x, f1.y);
    } else {
      return ((const float4*)hp)[(size_t)r * LPG + lane];
    }
  };

  float4 sv = loadrow(node);
  float4 acc = make_float4(di * sv.x, di * sv.y, di * sv.z, di * sv.w);

  const int e0 = row_start[node];
  const int e1 = row_start[node + 1];
  for (int e = e0; e < e1; ++e) {
    int s = csr_src[e];
    float w = csr_w[e];
    float4 v = loadrow(s);
    fma4(acc, w, v);
  }

  float4 b = ((const float4*)bias)[lane];
  acc.x = fmaf(di, acc.x, b.x);
  acc.y = fmaf(di, acc.y, b.y);
  acc.z = fmaf(di, acc.z, b.z);
  acc.w = fmaf(di, acc.w, b.w);

  if constexpr (SM) {
    float m = fmaxf(fmaxf(acc.x, acc.y), fmaxf(acc.z, acc.w));
#pragma unroll
    for (int off = LPG / 2; off >= 1; off >>= 1) m = fmaxf(m, __shfl_xor(m, off));
    float4 ex;
    ex.x = __expf(acc.x - m);
    ex.y = __expf(acc.y - m);
    ex.z = __expf(acc.z - m);
    ex.w = __expf(acc.w - m);
    float ssum = ex.x + ex.y + ex.z + ex.w;
#pragma unroll
    for (int off = LPG / 2; off >= 1; off >>= 1) ssum += __shfl_xor(ssum, off);
    float r = 1.0f / ssum;
    acc.x = ex.x * r;
    acc.y = ex.y * r;
    acc.z = ex.z * r;
    acc.w = ex.w * r;
  }

  ((float4*)out)[(size_t)node * LPG + lane] = acc;
}

extern "C" void kernel_launch(void* const* d_in, const int* in_sizes, int n_in,
                              void* d_out, int out_size, void* d_ws, size_t ws_size,
                              hipStream_t stream) {
  const float* x  = (const float*)d_in[0];
  const float* W1 = (const float*)d_in[1];
  const float* b1 = (const float*)d_in[2];
  const float* W2 = (const float*)d_in[3];
  const float* b2 = (const float*)d_in[4];
  const int*   ei = (const int*)d_in[5];

  const int N = in_sizes[0] / 128;
  const int E = in_sizes[5] / 2;
  const int NBK = (N + (1 << BSHIFT) - 1) >> BSHIFT;  // <= 1024 for N <= 131072
  const int* srcp = ei;
  const int* dstp = ei + E;

  auto align256 = [](size_t v) { return (v + 255) & ~(size_t)255; };
  char* ws = (char*)d_ws;
  size_t o_dinv   = 0;
  size_t o_rs     = align256(o_dinv + (size_t)N * 4);
  size_t o_bcnt   = align256(o_rs + (size_t)(N + 1) * 4);
  size_t o_bcur   = align256(o_bcnt + (size_t)1024 * BPAD * 4);
  size_t o_bstart = align256(o_bcur + (size_t)1024 * BPAD * 4);
  size_t o_stg    = align256(o_bstart + (size_t)1025 * 4);
  size_t o_csr    = align256(o_stg + (size_t)E * 4);
  size_t o_h1     = align256(o_csr + (size_t)E * 4);
  size_t o_s      = align256(o_h1 + (size_t)N * 128 * 4);

  float*    dinv     = (float*)(ws + o_dinv);
  int*      rowstart = (int*)(ws + o_rs);
  int*      bcnt     = (int*)(ws + o_bcnt);
  int*      bcur     = (int*)(ws + o_bcur);
  int*      bstart   = (int*)(ws + o_bstart);
  unsigned* staging  = (unsigned*)(ws + o_stg);  // reused as csr_w after finalize
  float*    csr_w    = (float*)(ws + o_stg);
  int*      csr_src  = (int*)(ws + o_csr);
  float*    h1       = (float*)(ws + o_h1);      // [N,128] fp32; reused as h2 [N,64] fp16
  float*    sbuf     = (float*)(ws + o_s);       // [N,128] softmax output

  // CSR build (two-level counting sort; all HBM writes coalesced)
  hipMemsetAsync(bcnt, 0, (size_t)NBK * BPAD * 4, stream);
  bucket_count<<<(E + 255) / 256, 256, 0, stream>>>(dstp, bcnt, E);
  bucket_scan<<<1, 1024, 0, stream>>>(bcnt, bstart, bcur, rowstart, NBK, N, E);
  bucket_scatter<<<(E + 255) / 256, 256, 0, stream>>>(srcp, dstp, bcur, staging, E);
  bucket_finalize<<<NBK, 256, 0, stream>>>(staging, bstart, csr_src, rowstart, dinv, N);
  make_w<<<(E + 255) / 256, 256, 0, stream>>>(csr_src, dinv, csr_w, E);

  // Layer 1
  gemm_k128<128, false><<<(N + 31) / 32, 256, 0, stream>>>(x, W1, h1, N);
  aggregate<128, true, false><<<(N + 7) / 8, 256, 0, stream>>>(h1, rowstart, csr_src,
                                                               csr_w, dinv, b1, sbuf, N);
  // Layer 2 (h2 in fp16, into h1's buffer)
  gemm_k128<64, true><<<(N + 63) / 64, 256, 0, stream>>>(sbuf, W2, h1, N);
  aggregate<64, false, true><<<(N + 15) / 16, 256, 0, stream>>>(h1, rowstart, csr_src,
                                                                csr_w, dinv, b2,
                                                                (float*)d_out, N);
}

// Round 3
// 394.928 us; speedup vs baseline: 1.4932x; 1.2247x over previous
//
#include <hip/hip_runtime.h>
#include <hip/hip_fp16.h>
#include <cstdint>
#include <cstddef>

// ---------------------------------------------------------------------------
// 2-layer GCN: h1 = x@W1; s = softmax(A_norm@h1 + b1); out = A_norm@(s@W2) + b2
// CSR build via two-level counting sort (coalesced HBM writes). Aggregation
// factored as out = di*(sum w_e*h[src_e] + di*h[node]) + b with per-edge
// (src, w=dinv[src]) packed as int2. All intermediates (h1, softmax, h2) in
// fp16 to halve random-gather bytes; fp32 accumulation everywhere.
// Edge loop unrolled x4 for memory-level parallelism.
// ---------------------------------------------------------------------------

#define BSHIFT 7              // 128 nodes per bucket
#define BPAD 16               // bucket counter padding (64B)
#define CAP 4096              // LDS reorder buffer (mean bucket ~2048 edges)

__device__ __forceinline__ void h8_to_f(const uint4& u, float* f) {
  const __half2* hp = (const __half2*)&u;
#pragma unroll
  for (int i = 0; i < 4; ++i) {
    float2 t = __half22float2(hp[i]);
    f[2 * i] = t.x;
    f[2 * i + 1] = t.y;
  }
}

__device__ __forceinline__ void fma8(float* acc, float w, const float* v) {
#pragma unroll
  for (int i = 0; i < 8; ++i) acc[i] = fmaf(w, v[i], acc[i]);
}

__global__ __launch_bounds__(256) void bucket_count(const int* __restrict__ dst,
                                                    int* __restrict__ bcnt, int E) {
  int e = blockIdx.x * 256 + threadIdx.x;
  if (e < E) atomicAdd(&bcnt[(dst[e] >> BSHIFT) * BPAD], 1);
}

__global__ __launch_bounds__(1024) void bucket_scan(const int* __restrict__ bcnt,
                                                    int* __restrict__ bstart,
                                                    int* __restrict__ bcur,
                                                    int* __restrict__ row_start,
                                                    int nb, int n, int E) {
  __shared__ int wsum[16];
  const int tid = threadIdx.x;
  const int lane = tid & 63;
  const int wid = tid >> 6;
  int v = (tid < nb) ? bcnt[tid * BPAD] : 0;
  int x = v;
#pragma unroll
  for (int d = 1; d < 64; d <<= 1) {
    int y = __shfl_up(x, d);
    if (lane >= d) x += y;
  }
  if (lane == 63) wsum[wid] = x;
  __syncthreads();
  if (wid == 0) {
    int w = (lane < 16) ? wsum[lane] : 0;
#pragma unroll
    for (int d = 1; d < 16; d <<= 1) {
      int y = __shfl_up(w, d);
      if (lane >= d) w += y;
    }
    if (lane < 16) wsum[lane] = w;
  }
  __syncthreads();
  int boff = (wid > 0) ? wsum[wid - 1] : 0;
  int incl = boff + x;
  if (tid < nb) {
    int excl = incl - v;
    bstart[tid] = excl;
    bcur[tid * BPAD] = excl;
    if (tid == nb - 1) bstart[nb] = incl;
  }
  if (tid == 0) row_start[n] = E;
}

__global__ __launch_bounds__(256) void bucket_scatter(const int* __restrict__ src,
                                                      const int* __restrict__ dst,
                                                      int* __restrict__ bcur,
                                                      unsigned* __restrict__ staging,
                                                      int E) {
  int e = blockIdx.x * 256 + threadIdx.x;
  if (e < E) {
    int d = dst[e];
    int p = atomicAdd(&bcur[(d >> BSHIFT) * BPAD], 1);
    staging[p] = ((unsigned)(d & ((1 << BSHIFT) - 1)) << 25) | (unsigned)src[e];
  }
}

__global__ __launch_bounds__(256) void bucket_finalize(const unsigned* __restrict__ staging,
                                                       const int* __restrict__ bstart,
                                                       int* __restrict__ csr_src,
                                                       int* __restrict__ row_start,
                                                       float* __restrict__ dinv, int n) {
  __shared__ int lcnt[128];
  __shared__ int lcur[128];
  __shared__ int w0tot;
  __shared__ int lbuf[CAP];
  const int b = blockIdx.x;
  const int tid = threadIdx.x;
  const int n0 = b << BSHIFT;
  const int s0 = bstart[b];
  const int cnt = bstart[b + 1] - s0;

  if (tid < 128) lcnt[tid] = 0;
  __syncthreads();
  for (int i = tid; i < cnt; i += 256) {
    unsigned p = staging[s0 + i];
    atomicAdd(&lcnt[p >> 25], 1);
  }
  __syncthreads();

  int v = 0, x = 0;
  const int lane = tid & 63;
  if (tid < 128) {
    v = lcnt[tid];
    x = v;
#pragma unroll
    for (int d = 1; d < 64; d <<= 1) {
      int y = __shfl_up(x, d);
      if (lane >= d) x += y;
    }
  }
  if (tid == 63) w0tot = x;
  __syncthreads();
  if (tid < 128) {
    int excl = x - v + ((tid >= 64) ? w0tot : 0);
    lcur[tid] = excl;
    int node = n0 + tid;
    if (node < n) {
      row_start[node] = s0 + excl;
      dinv[node] = rsqrtf((float)v + 1.0f);
    }
  }
  __syncthreads();

  for (int i = tid; i < cnt; i += 256) {
    unsigned p = staging[s0 + i];
    int dl = p >> 25;
    int src = (int)(p & 0x1FFFFFFu);
    int pos = atomicAdd(&lcur[dl], 1);
    if (pos < CAP) lbuf[pos] = src;
    else csr_src[s0 + pos] = src;
  }
  __syncthreads();
  const int lim = cnt < CAP ? cnt : CAP;
  for (int i = tid; i < lim; i += 256) csr_src[s0 + i] = lbuf[i];
}

__global__ __launch_bounds__(256) void make_pack(const int* __restrict__ csr_src,
                                                 const float* __restrict__ dinv,
                                                 int2* __restrict__ pack, int E) {
  int e = blockIdx.x * 256 + threadIdx.x;
  if (e < E) {
    int s = csr_src[e];
    pack[e] = make_int2(s, __float_as_int(dinv[s]));
  }
}

// H[N,M] = X[N,128] @ W[128,M].  W fully in LDS (k-major), X tile staged as
// fp32 in LDS (converted if fp16 input). fp16 output. 4x4 micro-tile.
template <int M, bool HIN>
__global__ __launch_bounds__(256) void gemm_k128(const void* __restrict__ Xp,
                                                 const float* __restrict__ W,
                                                 __half* __restrict__ H, int N) {
  constexpr int CT = M / 4;
  constexpr int RT = 256 / CT;
  constexpr int BM = RT * 4;
  __shared__ float Ws[128 * M];
  __shared__ float Xs[BM * 128];
  const int tid = threadIdx.x;
  const int r0 = blockIdx.x * BM;

  {
    const float4* Wv = (const float4*)W;
    float4* Wsv = (float4*)Ws;
    constexpr int TOT = 128 * M / 4;
#pragma unroll
    for (int i = tid; i < TOT; i += 256) Wsv[i] = Wv[i];
  }
  {
    float4* Xsv = (float4*)Xs;
    constexpr int TOT = BM * 32;
#pragma unroll
    for (int i = tid; i < TOT; i += 256) {
      int r = r0 + i / 32;
      int c = i % 32;
      int rr = (r < N) ? r : (N - 1);
      if constexpr (HIN) {
        const uint2* Xv = (const uint2*)Xp;
        uint2 u = Xv[(size_t)rr * 32 + c];
        __half2 h0 = *(__half2*)&u.x;
        __half2 h1 = *(__half2*)&u.y;
        float2 f0 = __half22float2(h0), f1 = __half22float2(h1);
        Xsv[i] = make_float4(f0.x, f0.y, f1.x, f1.y);
      } else {
        const float4* Xv = (const float4*)Xp;
        Xsv[i] = Xv[(size_t)rr * 32 + c];
      }
    }
  }
  __syncthreads();

  const int ct = tid % CT;
  const int rt = tid / CT;
  float4 acc[4];
#pragma unroll
  for (int i = 0; i < 4; ++i) acc[i] = make_float4(0.f, 0.f, 0.f, 0.f);

  const float* xb = &Xs[(4 * rt) * 128];
  const float* wb = &Ws[4 * ct];
#pragma unroll 4
  for (int k = 0; k < 128; k += 4) {
    float4 xq[4];
#pragma unroll
    for (int i = 0; i < 4; ++i) xq[i] = *(const float4*)&xb[i * 128 + k];
    float4 w0 = *(const float4*)&wb[(k + 0) * M];
    float4 w1 = *(const float4*)&wb[(k + 1) * M];
    float4 w2 = *(const float4*)&wb[(k + 2) * M];
    float4 w3 = *(const float4*)&wb[(k + 3) * M];
#pragma unroll
    for (int i = 0; i < 4; ++i) {
      acc[i].x = fmaf(xq[i].x, w0.x, acc[i].x);
      acc[i].y = fmaf(xq[i].x, w0.y, acc[i].y);
      acc[i].z = fmaf(xq[i].x, w0.z, acc[i].z);
      acc[i].w = fmaf(xq[i].x, w0.w, acc[i].w);
      acc[i].x = fmaf(xq[i].y, w1.x, acc[i].x);
      acc[i].y = fmaf(xq[i].y, w1.y, acc[i].y);
      acc[i].z = fmaf(xq[i].y, w1.z, acc[i].z);
      acc[i].w = fmaf(xq[i].y, w1.w, acc[i].w);
      acc[i].x = fmaf(xq[i].z, w2.x, acc[i].x);
      acc[i].y = fmaf(xq[i].z, w2.y, acc[i].y);
      acc[i].z = fmaf(xq[i].z, w2.z, acc[i].z);
      acc[i].w = fmaf(xq[i].z, w2.w, acc[i].w);
      acc[i].x = fmaf(xq[i].w, w3.x, acc[i].x);
      acc[i].y = fmaf(xq[i].w, w3.y, acc[i].y);
      acc[i].z = fmaf(xq[i].w, w3.z, acc[i].z);
      acc[i].w = fmaf(xq[i].w, w3.w, acc[i].w);
    }
  }

#pragma unroll
  for (int i = 0; i < 4; ++i) {
    int r = r0 + 4 * rt + i;
    if (r < N) {
      union { struct { __half2 a, b; } h; uint2 u; } cv;
      cv.h.a = __floats2half2_rn(acc[i].x, acc[i].y);
      cv.h.b = __floats2half2_rn(acc[i].z, acc[i].w);
      *(uint2*)&H[(size_t)r * M + 4 * ct] = cv.u;
    }
  }
}

// out[node] = di*( sum_e w_e*h[src_e] + di*h[node] ) + bias (+softmax).
// fp16 input rows of F halves; each lane owns 8 contiguous features (16B).
template <int F, bool SM, bool OUTHALF>
__global__ __launch_bounds__(256) void aggregate(const __half* __restrict__ h,
                                                 const int* __restrict__ row_start,
                                                 const int2* __restrict__ pack,
                                                 const float* __restrict__ dinv,
                                                 const float* __restrict__ bias,
                                                 void* __restrict__ out, int n) {
  constexpr int LPG = F / 8;
  constexpr int GPB = 256 / LPG;
  const int node = blockIdx.x * GPB + (int)(threadIdx.x / LPG);
  const int lane = threadIdx.x % LPG;
  if (node >= n) return;

  const uint4* hv = (const uint4*)h;
  const float di = dinv[node];

  float acc[8];
  {
    uint4 su = hv[(size_t)node * LPG + lane];
    float sf[8];
    h8_to_f(su, sf);
#pragma unroll
    for (int i = 0; i < 8; ++i) acc[i] = di * sf[i];
  }

  int e = row_start[node];
  const int e1 = row_start[node + 1];
  for (; e + 4 <= e1; e += 4) {
    int2 p0 = pack[e], p1 = pack[e + 1], p2 = pack[e + 2], p3 = pack[e + 3];
    uint4 r0 = hv[(size_t)p0.x * LPG + lane];
    uint4 r1 = hv[(size_t)p1.x * LPG + lane];
    uint4 r2 = hv[(size_t)p2.x * LPG + lane];
    uint4 r3 = hv[(size_t)p3.x * LPG + lane];
    float v[8];
    h8_to_f(r0, v); fma8(acc, __int_as_float(p0.y), v);
    h8_to_f(r1, v); fma8(acc, __int_as_float(p1.y), v);
    h8_to_f(r2, v); fma8(acc, __int_as_float(p2.y), v);
    h8_to_f(r3, v); fma8(acc, __int_as_float(p3.y), v);
  }
  for (; e < e1; ++e) {
    int2 p = pack[e];
    uint4 r = hv[(size_t)p.x * LPG + lane];
    float v[8];
    h8_to_f(r, v);
    fma8(acc, __int_as_float(p.y), v);
  }

  {
    const float4* bv = (const float4*)bias;
    float4 b0 = bv[lane * 2], b1 = bv[lane * 2 + 1];
    acc[0] = fmaf(di, acc[0], b0.x);
    acc[1] = fmaf(di, acc[1], b0.y);
    acc[2] = fmaf(di, acc[2], b0.z);
    acc[3] = fmaf(di, acc[3], b0.w);
    acc[4] = fmaf(di, acc[4], b1.x);
    acc[5] = fmaf(di, acc[5], b1.y);
    acc[6] = fmaf(di, acc[6], b1.z);
    acc[7] = fmaf(di, acc[7], b1.w);
  }

  if constexpr (SM) {
    float m = acc[0];
#pragma unroll
    for (int i = 1; i < 8; ++i) m = fmaxf(m, acc[i]);
#pragma unroll
    for (int off = LPG / 2; off >= 1; off >>= 1) m = fmaxf(m, __shfl_xor(m, off));
    float ex[8], ssum = 0.f;
#pragma unroll
    for (int i = 0; i < 8; ++i) {
      ex[i] = __expf(acc[i] - m);
      ssum += ex[i];
    }
#pragma unroll
    for (int off = LPG / 2; off >= 1; off >>= 1) ssum += __shfl_xor(ssum, off);
    float r = 1.0f / ssum;
#pragma unroll
    for (int i = 0; i < 8; ++i) acc[i] = ex[i] * r;
  }

  if constexpr (OUTHALF) {
    union { __half2 h[4]; uint4 u; } cv;
#pragma unroll
    for (int i = 0; i < 4; ++i)
      cv.h[i] = __floats2half2_rn(acc[2 * i], acc[2 * i + 1]);
    ((uint4*)out)[(size_t)node * LPG + lane] = cv.u;
  } else {
    float4* ov = (float4*)out;
    ov[(size_t)node * (F / 4) + lane * 2] =
        make_float4(acc[0], acc[1], acc[2], acc[3]);
    ov[(size_t)node * (F / 4) + lane * 2 + 1] =
        make_float4(acc[4], acc[5], acc[6], acc[7]);
  }
}

extern "C" void kernel_launch(void* const* d_in, const int* in_sizes, int n_in,
                              void* d_out, int out_size, void* d_ws, size_t ws_size,
                              hipStream_t stream) {
  const float* x  = (const float*)d_in[0];
  const float* W1 = (const float*)d_in[1];
  const float* b1 = (const float*)d_in[2];
  const float* W2 = (const float*)d_in[3];
  const float* b2 = (const float*)d_in[4];
  const int*   ei = (const int*)d_in[5];

  const int N = in_sizes[0] / 128;
  const int E = in_sizes[5] / 2;
  const int NBK = (N + (1 << BSHIFT) - 1) >> BSHIFT;
  const int* srcp = ei;
  const int* dstp = ei + E;

  auto align256 = [](size_t v) { return (v + 255) & ~(size_t)255; };
  char* ws = (char*)d_ws;
  size_t o_dinv   = 0;
  size_t o_rs     = align256(o_dinv + (size_t)N * 4);
  size_t o_bcnt   = align256(o_rs + (size_t)(N + 1) * 4);
  size_t o_bcur   = align256(o_bcnt + (size_t)1024 * BPAD * 4);
  size_t o_bstart = align256(o_bcur + (size_t)1024 * BPAD * 4);
  size_t o_stg    = align256(o_bstart + (size_t)1025 * 4);
  size_t o_csr    = align256(o_stg + (size_t)E * 4);
  size_t o_pack   = align256(o_csr + (size_t)E * 4);
  size_t o_h1     = align256(o_pack + (size_t)E * 8);
  size_t o_s      = align256(o_h1 + (size_t)N * 128 * 2);

  float*    dinv     = (float*)(ws + o_dinv);
  int*      rowstart = (int*)(ws + o_rs);
  int*      bcnt     = (int*)(ws + o_bcnt);
  int*      bcur     = (int*)(ws + o_bcur);
  int*      bstart   = (int*)(ws + o_bstart);
  unsigned* staging  = (unsigned*)(ws + o_stg);
  int*      csr_src  = (int*)(ws + o_csr);
  int2*     pack     = (int2*)(ws + o_pack);
  __half*   h1       = (__half*)(ws + o_h1);   // [N,128] fp16; reused as h2 [N,64]
  __half*   sbuf     = (__half*)(ws + o_s);    // [N,128] fp16 softmax output

  // CSR build
  hipMemsetAsync(bcnt, 0, (size_t)NBK * BPAD * 4, stream);
  bucket_count<<<(E + 255) / 256, 256, 0, stream>>>(dstp, bcnt, E);
  bucket_scan<<<1, 1024, 0, stream>>>(bcnt, bstart, bcur, rowstart, NBK, N, E);
  bucket_scatter<<<(E + 255) / 256, 256, 0, stream>>>(srcp, dstp, bcur, staging, E);
  bucket_finalize<<<NBK, 256, 0, stream>>>(staging, bstart, csr_src, rowstart, dinv, N);
  make_pack<<<(E + 255) / 256, 256, 0, stream>>>(csr_src, dinv, pack, E);

  // Layer 1
  gemm_k128<128, false><<<(N + 31) / 32, 256, 0, stream>>>(x, W1, h1, N);
  aggregate<128, true, true><<<(N + 15) / 16, 256, 0, stream>>>(h1, rowstart, pack,
                                                                dinv, b1, sbuf, N);
  // Layer 2
  gemm_k128<64, true><<<(N + 63) / 64, 256, 0, stream>>>(sbuf, W2, h1, N);
  aggregate<64, false, false><<<(N + 31) / 32, 256, 0, stream>>>(h1, rowstart, pack,
                                                                 dinv, b2, d_out, N);
}

// Round 4
// 269.210 us; speedup vs baseline: 2.1905x; 1.4670x over previous
//
#include <hip/hip_runtime.h>
#include <hip/hip_fp16.h>
#include <cstdint>
#include <cstddef>

// ---------------------------------------------------------------------------
// 2-layer GCN: h1 = x@W1; s = softmax(A_norm@h1 + b1); out = A_norm@(s@W2) + b2
// CSR build: wg-private two-level counting sort with ZERO global atomics.
//   - 256 edge slices, one workgroup each; LDS histogram over 391 buckets
//     (256 dst nodes per bucket) -> counts[wg][bucket]
//   - two tiny scans -> per-(wg,bucket) private output ranges
//   - scatter via LDS cursors: each staging line written by one CU (no
//     cross-XCD partial-line write amplification)
//   - per-bucket finalize: LDS histogram/scan/reorder -> row_start, dinv,
//     coalesced csr_src
// Aggregation: out = di*(sum w_e*h[src_e] + di*h[node]) + b, per-edge
// (src, w=dinv[src]) packed int2, fp16 intermediates, x8 unrolled gather.
// ---------------------------------------------------------------------------

#define BSHIFT 8              // 256 nodes per bucket
#define NBPAD 512             // padded bucket count (NB=391 for N=100K)
#define NWG 256               // edge slices / scatter workgroups
#define CAP 6144              // LDS reorder buffer (mean bucket ~4096 edges)

__device__ __forceinline__ void h8_to_f(const uint4& u, float* f) {
  const __half2* hp = (const __half2*)&u;
#pragma unroll
  for (int i = 0; i < 4; ++i) {
    float2 t = __half22float2(hp[i]);
    f[2 * i] = t.x;
    f[2 * i + 1] = t.y;
  }
}

__device__ __forceinline__ void fma8(float* acc, float w, const float* v) {
#pragma unroll
  for (int i = 0; i < 8; ++i) acc[i] = fmaf(w, v[i], acc[i]);
}

// inclusive scan of v across a 256-thread block; wsums is __shared__ int[4]
__device__ __forceinline__ int block_scan256(int v, int* wsums) {
  const int lane = threadIdx.x & 63;
  const int wid = threadIdx.x >> 6;
  int x = v;
#pragma unroll
  for (int d = 1; d < 64; d <<= 1) {
    int y = __shfl_up(x, d);
    if (lane >= d) x += y;
  }
  if (lane == 63) wsums[wid] = x;
  __syncthreads();
  int off = 0;
#pragma unroll
  for (int j = 0; j < 4; ++j)
    if (j < wid) off += wsums[j];
  return off + x;
}

// Pass 1: per-wg LDS histogram of its edge slice -> counts[wg*NBPAD + b]
__global__ __launch_bounds__(256) void wg_count(const int* __restrict__ dst,
                                                int* __restrict__ counts,
                                                int E, int nb, int slice) {
  __shared__ int lh[NBPAD];
  const int w = blockIdx.x;
  for (int i = threadIdx.x; i < nb; i += 256) lh[i] = 0;
  __syncthreads();
  const int e0 = w * slice;
  const int e1 = min(e0 + slice, E);
  for (int e = e0 + threadIdx.x; e < e1; e += 256)
    atomicAdd(&lh[dst[e] >> BSHIFT], 1);
  __syncthreads();
  for (int i = threadIdx.x; i < nb; i += 256) counts[(size_t)w * NBPAD + i] = lh[i];
}

// Pass 2: single block — per-bucket totals + exclusive scan -> bstart[0..nb]
__global__ __launch_bounds__(1024) void scan_buckets(const int* __restrict__ counts,
                                                     int* __restrict__ bstart,
                                                     int* __restrict__ row_start,
                                                     int nb, int n, int E) {
  __shared__ int wsum[16];
  const int tid = threadIdx.x;
  const int lane = tid & 63;
  const int wid = tid >> 6;
  int v = 0;
  if (tid < nb) {
#pragma unroll 4
    for (int i = 0; i < NWG; ++i) v += counts[(size_t)i * NBPAD + tid];
  }
  int x = v;
#pragma unroll
  for (int d = 1; d < 64; d <<= 1) {
    int y = __shfl_up(x, d);
    if (lane >= d) x += y;
  }
  if (lane == 63) wsum[wid] = x;
  __syncthreads();
  if (wid == 0) {
    int w = (lane < 16) ? wsum[lane] : 0;
#pragma unroll
    for (int d = 1; d < 16; d <<= 1) {
      int y = __shfl_up(w, d);
      if (lane >= d) w += y;
    }
    if (lane < 16) wsum[lane] = w;
  }
  __syncthreads();
  int boff = (wid > 0) ? wsum[wid - 1] : 0;
  int incl = boff + x;
  if (tid < nb) {
    bstart[tid] = incl - v;
    if (tid == nb - 1) bstart[nb] = incl;
  }
  if (tid == 0) row_start[n] = E;
}

// Pass 3: one block per bucket — exclusive scan across wgs -> cur[wg][b]
__global__ __launch_bounds__(256) void cell_scan(const int* __restrict__ counts,
                                                 const int* __restrict__ bstart,
                                                 int* __restrict__ cur, int nb) {
  __shared__ int wsums[4];
  const int b = blockIdx.x;
  const int tid = threadIdx.x;
  int v = counts[(size_t)tid * NBPAD + b];
  int incl = block_scan256(v, wsums);
  cur[(size_t)tid * NBPAD + b] = bstart[b] + incl - v;
}

// Pass 4: scatter with LDS cursors — each (wg,bucket) range written by one wg
__global__ __launch_bounds__(256) void wg_scatter(const int* __restrict__ src,
                                                  const int* __restrict__ dst,
                                                  const int* __restrict__ cur,
                                                  unsigned* __restrict__ staging,
                                                  int E, int nb, int slice) {
  __shared__ int lc[NBPAD];
  const int w = blockIdx.x;
  for (int i = threadIdx.x; i < nb; i += 256) lc[i] = cur[(size_t)w * NBPAD + i];
  __syncthreads();
  const int e0 = w * slice;
  const int e1 = min(e0 + slice, E);
  for (int e = e0 + threadIdx.x; e < e1; e += 256) {
    int d = dst[e];
    int p = atomicAdd(&lc[d >> BSHIFT], 1);
    staging[p] = ((unsigned)(d & 255) << 24) | (unsigned)src[e];
  }
}

// Pass 5: per-bucket finalize — row_start, dinv, coalesced csr_src
__global__ __launch_bounds__(256) void bucket_finalize(const unsigned* __restrict__ staging,
                                                       const int* __restrict__ bstart,
                                                       int* __restrict__ csr_src,
                                                       int* __restrict__ row_start,
                                                       float* __restrict__ dinv, int n) {
  __shared__ int lcnt[256];
  __shared__ int lcur[256];
  __shared__ int wsums[4];
  __shared__ int lbuf[CAP];
  const int b = blockIdx.x;
  const int tid = threadIdx.x;
  const int n0 = b << BSHIFT;
  const int s0 = bstart[b];
  const int cnt = bstart[b + 1] - s0;

  lcnt[tid] = 0;
  __syncthreads();
  for (int i = tid; i < cnt; i += 256)
    atomicAdd(&lcnt[staging[s0 + i] >> 24], 1);
  __syncthreads();

  const int v = lcnt[tid];
  const int incl = block_scan256(v, wsums);
  const int excl = incl - v;
  lcur[tid] = excl;
  const int node = n0 + tid;
  if (node < n) {
    row_start[node] = s0 + excl;
    dinv[node] = rsqrtf((float)v + 1.0f);
  }
  __syncthreads();

  for (int i = tid; i < cnt; i += 256) {
    unsigned p = staging[s0 + i];
    int pos = atomicAdd(&lcur[p >> 24], 1);
    int s = (int)(p & 0xFFFFFFu);
    if (pos < CAP) lbuf[pos] = s;
    else csr_src[s0 + pos] = s;  // overflow fallback (statistically never)
  }
  __syncthreads();
  const int lim = cnt < CAP ? cnt : CAP;
  for (int i = tid; i < lim; i += 256) csr_src[s0 + i] = lbuf[i];
}

__global__ __launch_bounds__(256) void make_pack(const int* __restrict__ csr_src,
                                                 const float* __restrict__ dinv,
                                                 int2* __restrict__ pack, int E) {
  int e = blockIdx.x * 256 + threadIdx.x;
  if (e < E) {
    int s = csr_src[e];
    pack[e] = make_int2(s, __float_as_int(dinv[s]));
  }
}

// H[N,M] = X[N,128] @ W[128,M].  W fully in LDS (k-major), X tile staged as
// fp32 in LDS (converted if fp16 input). fp16 output. 4x4 micro-tile.
template <int M, bool HIN>
__global__ __launch_bounds__(256) void gemm_k128(const void* __restrict__ Xp,
                                                 const float* __restrict__ W,
                                                 __half* __restrict__ H, int N) {
  constexpr int CT = M / 4;
  constexpr int RT = 256 / CT;
  constexpr int BM = RT * 4;
  __shared__ float Ws[128 * M];
  __shared__ float Xs[BM * 128];
  const int tid = threadIdx.x;
  const int r0 = blockIdx.x * BM;

  {
    const float4* Wv = (const float4*)W;
    float4* Wsv = (float4*)Ws;
    constexpr int TOT = 128 * M / 4;
#pragma unroll
    for (int i = tid; i < TOT; i += 256) Wsv[i] = Wv[i];
  }
  {
    float4* Xsv = (float4*)Xs;
    constexpr int TOT = BM * 32;
#pragma unroll
    for (int i = tid; i < TOT; i += 256) {
      int r = r0 + i / 32;
      int c = i % 32;
      int rr = (r < N) ? r : (N - 1);
      if constexpr (HIN) {
        const uint2* Xv = (const uint2*)Xp;
        uint2 u = Xv[(size_t)rr * 32 + c];
        __half2 h0 = *(__half2*)&u.x;
        __half2 h1 = *(__half2*)&u.y;
        float2 f0 = __half22float2(h0), f1 = __half22float2(h1);
        Xsv[i] = make_float4(f0.x, f0.y, f1.x, f1.y);
      } else {
        const float4* Xv = (const float4*)Xp;
        Xsv[i] = Xv[(size_t)rr * 32 + c];
      }
    }
  }
  __syncthreads();

  const int ct = tid % CT;
  const int rt = tid / CT;
  float4 acc[4];
#pragma unroll
  for (int i = 0; i < 4; ++i) acc[i] = make_float4(0.f, 0.f, 0.f, 0.f);

  const float* xb = &Xs[(4 * rt) * 128];
  const float* wb = &Ws[4 * ct];
#pragma unroll 4
  for (int k = 0; k < 128; k += 4) {
    float4 xq[4];
#pragma unroll
    for (int i = 0; i < 4; ++i) xq[i] = *(const float4*)&xb[i * 128 + k];
    float4 w0 = *(const float4*)&wb[(k + 0) * M];
    float4 w1 = *(const float4*)&wb[(k + 1) * M];
    float4 w2 = *(const float4*)&wb[(k + 2) * M];
    float4 w3 = *(const float4*)&wb[(k + 3) * M];
#pragma unroll
    for (int i = 0; i < 4; ++i) {
      acc[i].x = fmaf(xq[i].x, w0.x, acc[i].x);
      acc[i].y = fmaf(xq[i].x, w0.y, acc[i].y);
      acc[i].z = fmaf(xq[i].x, w0.z, acc[i].z);
      acc[i].w = fmaf(xq[i].x, w0.w, acc[i].w);
      acc[i].x = fmaf(xq[i].y, w1.x, acc[i].x);
      acc[i].y = fmaf(xq[i].y, w1.y, acc[i].y);
      acc[i].z = fmaf(xq[i].y, w1.z, acc[i].z);
      acc[i].w = fmaf(xq[i].y, w1.w, acc[i].w);
      acc[i].x = fmaf(xq[i].z, w2.x, acc[i].x);
      acc[i].y = fmaf(xq[i].z, w2.y, acc[i].y);
      acc[i].z = fmaf(xq[i].z, w2.z, acc[i].z);
      acc[i].w = fmaf(xq[i].z, w2.w, acc[i].w);
      acc[i].x = fmaf(xq[i].w, w3.x, acc[i].x);
      acc[i].y = fmaf(xq[i].w, w3.y, acc[i].y);
      acc[i].z = fmaf(xq[i].w, w3.z, acc[i].z);
      acc[i].w = fmaf(xq[i].w, w3.w, acc[i].w);
    }
  }

#pragma unroll
  for (int i = 0; i < 4; ++i) {
    int r = r0 + 4 * rt + i;
    if (r < N) {
      union { struct { __half2 a, b; } h; uint2 u; } cv;
      cv.h.a = __floats2half2_rn(acc[i].x, acc[i].y);
      cv.h.b = __floats2half2_rn(acc[i].z, acc[i].w);
      *(uint2*)&H[(size_t)r * M + 4 * ct] = cv.u;
    }
  }
}

// out[node] = di*( sum_e w_e*h[src_e] + di*h[node] ) + bias (+softmax).
// fp16 input rows of F halves; each lane owns 8 contiguous features (16B).
// Gather unrolled x8 for MLP.
template <int F, bool SM, bool OUTHALF>
__global__ __launch_bounds__(256) void aggregate(const __half* __restrict__ h,
                                                 const int* __restrict__ row_start,
                                                 const int2* __restrict__ pack,
                                                 const float* __restrict__ dinv,
                                                 const float* __restrict__ bias,
                                                 void* __restrict__ out, int n) {
  constexpr int LPG = F / 8;
  constexpr int GPB = 256 / LPG;
  const int node = blockIdx.x * GPB + (int)(threadIdx.x / LPG);
  const int lane = threadIdx.x % LPG;
  if (node >= n) return;

  const uint4* hv = (const uint4*)h;
  const float di = dinv[node];

  float acc[8];
  {
    uint4 su = hv[(size_t)node * LPG + lane];
    float sf[8];
    h8_to_f(su, sf);
#pragma unroll
    for (int i = 0; i < 8; ++i) acc[i] = di * sf[i];
  }

  int e = row_start[node];
  const int e1 = row_start[node + 1];
  for (; e + 8 <= e1; e += 8) {
    int2 p[8];
    uint4 r[8];
#pragma unroll
    for (int j = 0; j < 8; ++j) p[j] = pack[e + j];
#pragma unroll
    for (int j = 0; j < 8; ++j) r[j] = hv[(size_t)p[j].x * LPG + lane];
#pragma unroll
    for (int j = 0; j < 8; ++j) {
      float v[8];
      h8_to_f(r[j], v);
      fma8(acc, __int_as_float(p[j].y), v);
    }
  }
  for (; e + 4 <= e1; e += 4) {
    int2 p[4];
    uint4 r[4];
#pragma unroll
    for (int j = 0; j < 4; ++j) p[j] = pack[e + j];
#pragma unroll
    for (int j = 0; j < 4; ++j) r[j] = hv[(size_t)p[j].x * LPG + lane];
#pragma unroll
    for (int j = 0; j < 4; ++j) {
      float v[8];
      h8_to_f(r[j], v);
      fma8(acc, __int_as_float(p[j].y), v);
    }
  }
  for (; e < e1; ++e) {
    int2 p = pack[e];
    uint4 r = hv[(size_t)p.x * LPG + lane];
    float v[8];
    h8_to_f(r, v);
    fma8(acc, __int_as_float(p.y), v);
  }

  {
    const float4* bv = (const float4*)bias;
    float4 b0 = bv[lane * 2], b1 = bv[lane * 2 + 1];
    acc[0] = fmaf(di, acc[0], b0.x);
    acc[1] = fmaf(di, acc[1], b0.y);
    acc[2] = fmaf(di, acc[2], b0.z);
    acc[3] = fmaf(di, acc[3], b0.w);
    acc[4] = fmaf(di, acc[4], b1.x);
    acc[5] = fmaf(di, acc[5], b1.y);
    acc[6] = fmaf(di, acc[6], b1.z);
    acc[7] = fmaf(di, acc[7], b1.w);
  }

  if constexpr (SM) {
    float m = acc[0];
#pragma unroll
    for (int i = 1; i < 8; ++i) m = fmaxf(m, acc[i]);
#pragma unroll
    for (int off = LPG / 2; off >= 1; off >>= 1) m = fmaxf(m, __shfl_xor(m, off));
    float ex[8], ssum = 0.f;
#pragma unroll
    for (int i = 0; i < 8; ++i) {
      ex[i] = __expf(acc[i] - m);
      ssum += ex[i];
    }
#pragma unroll
    for (int off = LPG / 2; off >= 1; off >>= 1) ssum += __shfl_xor(ssum, off);
    float r = 1.0f / ssum;
#pragma unroll
    for (int i = 0; i < 8; ++i) acc[i] = ex[i] * r;
  }

  if constexpr (OUTHALF) {
    union { __half2 h[4]; uint4 u; } cv;
#pragma unroll
    for (int i = 0; i < 4; ++i)
      cv.h[i] = __floats2half2_rn(acc[2 * i], acc[2 * i + 1]);
    ((uint4*)out)[(size_t)node * LPG + lane] = cv.u;
  } else {
    float4* ov = (float4*)out;
    ov[(size_t)node * (F / 4) + lane * 2] =
        make_float4(acc[0], acc[1], acc[2], acc[3]);
    ov[(size_t)node * (F / 4) + lane * 2 + 1] =
        make_float4(acc[4], acc[5], acc[6], acc[7]);
  }
}

extern "C" void kernel_launch(void* const* d_in, const int* in_sizes, int n_in,
                              void* d_out, int out_size, void* d_ws, size_t ws_size,
                              hipStream_t stream) {
  const float* x  = (const float*)d_in[0];
  const float* W1 = (const float*)d_in[1];
  const float* b1 = (const float*)d_in[2];
  const float* W2 = (const float*)d_in[3];
  const float* b2 = (const float*)d_in[4];
  const int*   ei = (const int*)d_in[5];

  const int N = in_sizes[0] / 128;
  const int E = in_sizes[5] / 2;
  const int NB = (N + 255) >> BSHIFT;          // 391 for N=100K (<= NBPAD)
  const int SLICE = (E + NWG - 1) / NWG;
  const int* srcp = ei;
  const int* dstp = ei + E;

  auto align256 = [](size_t v) { return (v + 255) & ~(size_t)255; };
  char* ws = (char*)d_ws;
  size_t o_dinv   = 0;
  size_t o_rs     = align256(o_dinv + (size_t)N * 4);
  size_t o_cnts   = align256(o_rs + (size_t)(N + 1) * 4);
  size_t o_cur    = align256(o_cnts + (size_t)NWG * NBPAD * 4);
  size_t o_bstart = align256(o_cur + (size_t)NWG * NBPAD * 4);
  size_t o_stg    = align256(o_bstart + (size_t)(NBPAD + 1) * 4);
  size_t o_csr    = align256(o_stg + (size_t)E * 4);
  size_t o_pack   = align256(o_csr + (size_t)E * 4);
  size_t o_h1     = align256(o_pack + (size_t)E * 8);
  size_t o_s      = align256(o_h1 + (size_t)N * 128 * 2);

  float*    dinv     = (float*)(ws + o_dinv);
  int*      rowstart = (int*)(ws + o_rs);
  int*      counts   = (int*)(ws + o_cnts);
  int*      cur      = (int*)(ws + o_cur);
  int*      bstart   = (int*)(ws + o_bstart);
  unsigned* staging  = (unsigned*)(ws + o_stg);
  int*      csr_src  = (int*)(ws + o_csr);
  int2*     pack     = (int2*)(ws + o_pack);
  __half*   h1       = (__half*)(ws + o_h1);   // [N,128] fp16; reused as h2 [N,64]
  __half*   sbuf     = (__half*)(ws + o_s);    // [N,128] fp16 softmax output

  // CSR build — no global atomics anywhere
  wg_count<<<NWG, 256, 0, stream>>>(dstp, counts, E, NB, SLICE);
  scan_buckets<<<1, 1024, 0, stream>>>(counts, bstart, rowstart, NB, N, E);
  cell_scan<<<NB, 256, 0, stream>>>(counts, bstart, cur, NB);
  wg_scatter<<<NWG, 256, 0, stream>>>(srcp, dstp, cur, staging, E, NB, SLICE);
  bucket_finalize<<<NB, 256, 0, stream>>>(staging, bstart, csr_src, rowstart, dinv, N);
  make_pack<<<(E + 255) / 256, 256, 0, stream>>>(csr_src, dinv, pack, E);

  // Layer 1
  gemm_k128<128, false><<<(N + 31) / 32, 256, 0, stream>>>(x, W1, h1, N);
  aggregate<128, true, true><<<(N + 15) / 16, 256, 0, stream>>>(h1, rowstart, pack,
                                                                dinv, b1, sbuf, N);
  // Layer 2
  gemm_k128<64, true><<<(N + 63) / 64, 256, 0, stream>>>(sbuf, W2, h1, N);
  aggregate<64, false, false><<<(N + 31) / 32, 256, 0, stream>>>(h1, rowstart, pack,
                                                                 dinv, b2, d_out, N);
}

// Round 5
// 215.223 us; speedup vs baseline: 2.7400x; 1.2508x over previous
//
#include <hip/hip_runtime.h>
#include <hip/hip_fp16.h>
#include <cstdint>
#include <cstddef>

// ---------------------------------------------------------------------------
// 2-layer GCN: h1 = x@W1; s = softmax(A_norm@h1 + b1); out = A_norm@(s@W2) + b2
// CSR build: wg-private two-level counting sort (zero global atomics).
// GEMMs: fp16 MFMA (v_mfma_f32_16x16x32_f16), zero LDS; W pre-packed into
// per-lane fragment order so B-loads are single 16B dwordx4 from L2.
// Aggregation: out = di*(sum w_e*h[src_e] + di*h[node]) + b, packed (src,w)
// int2 stream, fp16 intermediates, x8 unrolled gather.
// ---------------------------------------------------------------------------

#define BSHIFT 8              // 256 nodes per bucket
#define NBPAD 512             // padded bucket count (NB=391 for N=100K)
#define NWG 256               // edge slices / scatter workgroups
#define CAP 6144              // LDS reorder buffer (mean bucket ~4096 edges)

typedef _Float16 half8 __attribute__((ext_vector_type(8)));
typedef float f32x4 __attribute__((ext_vector_type(4)));

__device__ __forceinline__ void h8_to_f(const uint4& u, float* f) {
  const __half2* hp = (const __half2*)&u;
#pragma unroll
  for (int i = 0; i < 4; ++i) {
    float2 t = __half22float2(hp[i]);
    f[2 * i] = t.x;
    f[2 * i + 1] = t.y;
  }
}

__device__ __forceinline__ void fma8(float* acc, float w, const float* v) {
#pragma unroll
  for (int i = 0; i < 8; ++i) acc[i] = fmaf(w, v[i], acc[i]);
}

// inclusive scan of v across a 256-thread block; wsums is __shared__ int[4]
__device__ __forceinline__ int block_scan256(int v, int* wsums) {
  const int lane = threadIdx.x & 63;
  const int wid = threadIdx.x >> 6;
  int x = v;
#pragma unroll
  for (int d = 1; d < 64; d <<= 1) {
    int y = __shfl_up(x, d);
    if (lane >= d) x += y;
  }
  if (lane == 63) wsums[wid] = x;
  __syncthreads();
  int off = 0;
#pragma unroll
  for (int j = 0; j < 4; ++j)
    if (j < wid) off += wsums[j];
  return off + x;
}

// Pass 1: per-wg LDS histogram of its edge slice -> counts[wg*NBPAD + b]
__global__ __launch_bounds__(256) void wg_count(const int* __restrict__ dst,
                                                int* __restrict__ counts,
                                                int E, int nb, int slice) {
  __shared__ int lh[NBPAD];
  const int w = blockIdx.x;
  for (int i = threadIdx.x; i < nb; i += 256) lh[i] = 0;
  __syncthreads();
  const int e0 = w * slice;
  const int e1 = min(e0 + slice, E);
  for (int e = e0 + threadIdx.x; e < e1; e += 256)
    atomicAdd(&lh[dst[e] >> BSHIFT], 1);
  __syncthreads();
  for (int i = threadIdx.x; i < nb; i += 256) counts[(size_t)w * NBPAD + i] = lh[i];
}

// Pass 2: single block — per-bucket totals + exclusive scan -> bstart[0..nb]
__global__ __launch_bounds__(1024) void scan_buckets(const int* __restrict__ counts,
                                                     int* __restrict__ bstart,
                                                     int* __restrict__ row_start,
                                                     int nb, int n, int E) {
  __shared__ int wsum[16];
  const int tid = threadIdx.x;
  const int lane = tid & 63;
  const int wid = tid >> 6;
  int v = 0;
  if (tid < nb) {
#pragma unroll 4
    for (int i = 0; i < NWG; ++i) v += counts[(size_t)i * NBPAD + tid];
  }
  int x = v;
#pragma unroll
  for (int d = 1; d < 64; d <<= 1) {
    int y = __shfl_up(x, d);
    if (lane >= d) x += y;
  }
  if (lane == 63) wsum[wid] = x;
  __syncthreads();
  if (wid == 0) {
    int w = (lane < 16) ? wsum[lane] : 0;
#pragma unroll
    for (int d = 1; d < 16; d <<= 1) {
      int y = __shfl_up(w, d);
      if (lane >= d) w += y;
    }
    if (lane < 16) wsum[lane] = w;
  }
  __syncthreads();
  int boff = (wid > 0) ? wsum[wid - 1] : 0;
  int incl = boff + x;
  if (tid < nb) {
    bstart[tid] = incl - v;
    if (tid == nb - 1) bstart[nb] = incl;
  }
  if (tid == 0) row_start[n] = E;
}

// Pass 3: one block per bucket — exclusive scan across wgs -> cur[wg][b]
__global__ __launch_bounds__(256) void cell_scan(const int* __restrict__ counts,
                                                 const int* __restrict__ bstart,
                                                 int* __restrict__ cur, int nb) {
  __shared__ int wsums[4];
  const int b = blockIdx.x;
  const int tid = threadIdx.x;
  int v = counts[(size_t)tid * NBPAD + b];
  int incl = block_scan256(v, wsums);
  cur[(size_t)tid * NBPAD + b] = bstart[b] + incl - v;
}

// Pass 4: scatter with LDS cursors — each (wg,bucket) range written by one wg
__global__ __launch_bounds__(256) void wg_scatter(const int* __restrict__ src,
                                                  const int* __restrict__ dst,
                                                  const int* __restrict__ cur,
                                                  unsigned* __restrict__ staging,
                                                  int E, int nb, int slice) {
  __shared__ int lc[NBPAD];
  const int w = blockIdx.x;
  for (int i = threadIdx.x; i < nb; i += 256) lc[i] = cur[(size_t)w * NBPAD + i];
  __syncthreads();
  const int e0 = w * slice;
  const int e1 = min(e0 + slice, E);
  for (int e = e0 + threadIdx.x; e < e1; e += 256) {
    int d = dst[e];
    int p = atomicAdd(&lc[d >> BSHIFT], 1);
    staging[p] = ((unsigned)(d & 255) << 24) | (unsigned)src[e];
  }
}

// Pass 5: per-bucket finalize — row_start, dinv, coalesced csr_src
__global__ __launch_bounds__(256) void bucket_finalize(const unsigned* __restrict__ staging,
                                                       const int* __restrict__ bstart,
                                                       int* __restrict__ csr_src,
                                                       int* __restrict__ row_start,
                                                       float* __restrict__ dinv, int n) {
  __shared__ int lcnt[256];
  __shared__ int lcur[256];
  __shared__ int wsums[4];
  __shared__ int lbuf[CAP];
  const int b = blockIdx.x;
  const int tid = threadIdx.x;
  const int n0 = b << BSHIFT;
  const int s0 = bstart[b];
  const int cnt = bstart[b + 1] - s0;

  lcnt[tid] = 0;
  __syncthreads();
  for (int i = tid; i < cnt; i += 256)
    atomicAdd(&lcnt[staging[s0 + i] >> 24], 1);
  __syncthreads();

  const int v = lcnt[tid];
  const int incl = block_scan256(v, wsums);
  const int excl = incl - v;
  lcur[tid] = excl;
  const int node = n0 + tid;
  if (node < n) {
    row_start[node] = s0 + excl;
    dinv[node] = rsqrtf((float)v + 1.0f);
  }
  __syncthreads();

  for (int i = tid; i < cnt; i += 256) {
    unsigned p = staging[s0 + i];
    int pos = atomicAdd(&lcur[p >> 24], 1);
    int s = (int)(p & 0xFFFFFFu);
    if (pos < CAP) lbuf[pos] = s;
    else csr_src[s0 + pos] = s;  // overflow fallback (statistically never)
  }
  __syncthreads();
  const int lim = cnt < CAP ? cnt : CAP;
  for (int i = tid; i < lim; i += 256) csr_src[s0 + i] = lbuf[i];
}

__global__ __launch_bounds__(256) void make_pack(const int* __restrict__ csr_src,
                                                 const float* __restrict__ dinv,
                                                 int2* __restrict__ pack, int E) {
  int e = blockIdx.x * 256 + threadIdx.x;
  if (e < E) {
    int s = csr_src[e];
    pack[e] = make_int2(s, __float_as_int(dinv[s]));
  }
}

// Pack W[128][M] fp32 -> Wp fp16 fragment order:
// Wp[((t*M + c)*4 + g)*8 + j] = W[t*32 + g*8 + j][c]
template <int M>
__global__ __launch_bounds__(256) void pack_w(const float* __restrict__ W,
                                              _Float16* __restrict__ Wp) {
  int e = blockIdx.x * 256 + threadIdx.x;
  if (e < 128 * M) {
    int k = e / M, c = e % M;
    int t = k >> 5, g = (k >> 3) & 3, j = k & 7;
    Wp[(((size_t)t * M + c) * 4 + g) * 8 + j] = (_Float16)W[e];
  }
}

// H[N,M] = X[N,128] @ W[128,M] via v_mfma_f32_16x16x32_f16. Zero LDS.
// Wave w handles rows [row0, row0+16); lane: r=lane&15, g=lane>>4.
// A frag: X[row0+r][32t + 8g + j]; B frag: Wp (packed); D: H[row0+4g+i][16c+r].
template <int M, bool HIN>
__global__ __launch_bounds__(256) void gemm_mfma(const void* __restrict__ Xp,
                                                 const _Float16* __restrict__ Wp,
                                                 _Float16* __restrict__ H, int N) {
  constexpr int CT = M / 16;
  const int wave = threadIdx.x >> 6;
  const int lane = threadIdx.x & 63;
  const int row0 = (blockIdx.x * 4 + wave) * 16;
  if (row0 >= N) return;
  const int r = lane & 15;
  const int g = lane >> 4;
  int row = row0 + r;
  if (row >= N) row = N - 1;

  f32x4 acc[CT];
#pragma unroll
  for (int c = 0; c < CT; ++c) acc[c] = (f32x4){0.f, 0.f, 0.f, 0.f};

#pragma unroll
  for (int t = 0; t < 4; ++t) {
    half8 a;
    if constexpr (HIN) {
      a = *(const half8*)((const _Float16*)Xp + (size_t)row * 128 + t * 32 + g * 8);
    } else {
      const float* xp = (const float*)Xp + (size_t)row * 128 + t * 32 + g * 8;
      float4 x0 = *(const float4*)xp;
      float4 x1 = *(const float4*)(xp + 4);
      a[0] = (_Float16)x0.x; a[1] = (_Float16)x0.y;
      a[2] = (_Float16)x0.z; a[3] = (_Float16)x0.w;
      a[4] = (_Float16)x1.x; a[5] = (_Float16)x1.y;
      a[6] = (_Float16)x1.z; a[7] = (_Float16)x1.w;
    }
#pragma unroll
    for (int c = 0; c < CT; ++c) {
      half8 b = *(const half8*)(Wp + (((size_t)t * M + c * 16 + r) * 4 + g) * 8);
      acc[c] = __builtin_amdgcn_mfma_f32_16x16x32_f16(a, b, acc[c], 0, 0, 0);
    }
  }

#pragma unroll
  for (int c = 0; c < CT; ++c) {
#pragma unroll
    for (int i = 0; i < 4; ++i) {
      int rr = row0 + 4 * g + i;
      if (rr < N) H[(size_t)rr * M + c * 16 + r] = (_Float16)acc[c][i];
    }
  }
}

// out[node] = di*( sum_e w_e*h[src_e] + di*h[node] ) + bias (+softmax).
// fp16 input rows of F halves; each lane owns 8 contiguous features (16B).
template <int F, bool SM, bool OUTHALF>
__global__ __launch_bounds__(256) void aggregate(const __half* __restrict__ h,
                                                 const int* __restrict__ row_start,
                                                 const int2* __restrict__ pack,
                                                 const float* __restrict__ dinv,
                                                 const float* __restrict__ bias,
                                                 void* __restrict__ out, int n) {
  constexpr int LPG = F / 8;
  constexpr int GPB = 256 / LPG;
  const int node = blockIdx.x * GPB + (int)(threadIdx.x / LPG);
  const int lane = threadIdx.x % LPG;
  if (node >= n) return;

  const uint4* hv = (const uint4*)h;
  const float di = dinv[node];

  float acc[8];
  {
    uint4 su = hv[(size_t)node * LPG + lane];
    float sf[8];
    h8_to_f(su, sf);
#pragma unroll
    for (int i = 0; i < 8; ++i) acc[i] = di * sf[i];
  }

  int e = row_start[node];
  const int e1 = row_start[node + 1];
  for (; e + 8 <= e1; e += 8) {
    int2 p[8];
    uint4 r[8];
#pragma unroll
    for (int j = 0; j < 8; ++j) p[j] = pack[e + j];
#pragma unroll
    for (int j = 0; j < 8; ++j) r[j] = hv[(size_t)p[j].x * LPG + lane];
#pragma unroll
    for (int j = 0; j < 8; ++j) {
      float v[8];
      h8_to_f(r[j], v);
      fma8(acc, __int_as_float(p[j].y), v);
    }
  }
  for (; e + 4 <= e1; e += 4) {
    int2 p[4];
    uint4 r[4];
#pragma unroll
    for (int j = 0; j < 4; ++j) p[j] = pack[e + j];
#pragma unroll
    for (int j = 0; j < 4; ++j) r[j] = hv[(size_t)p[j].x * LPG + lane];
#pragma unroll
    for (int j = 0; j < 4; ++j) {
      float v[8];
      h8_to_f(r[j], v);
      fma8(acc, __int_as_float(p[j].y), v);
    }
  }
  for (; e < e1; ++e) {
    int2 p = pack[e];
    uint4 r = hv[(size_t)p.x * LPG + lane];
    float v[8];
    h8_to_f(r, v);
    fma8(acc, __int_as_float(p.y), v);
  }

  {
    const float4* bv = (const float4*)bias;
    float4 b0 = bv[lane * 2], b1 = bv[lane * 2 + 1];
    acc[0] = fmaf(di, acc[0], b0.x);
    acc[1] = fmaf(di, acc[1], b0.y);
    acc[2] = fmaf(di, acc[2], b0.z);
    acc[3] = fmaf(di, acc[3], b0.w);
    acc[4] = fmaf(di, acc[4], b1.x);
    acc[5] = fmaf(di, acc[5], b1.y);
    acc[6] = fmaf(di, acc[6], b1.z);
    acc[7] = fmaf(di, acc[7], b1.w);
  }

  if constexpr (SM) {
    float m = acc[0];
#pragma unroll
    for (int i = 1; i < 8; ++i) m = fmaxf(m, acc[i]);
#pragma unroll
    for (int off = LPG / 2; off >= 1; off >>= 1) m = fmaxf(m, __shfl_xor(m, off));
    float ex[8], ssum = 0.f;
#pragma unroll
    for (int i = 0; i < 8; ++i) {
      ex[i] = __expf(acc[i] - m);
      ssum += ex[i];
    }
#pragma unroll
    for (int off = LPG / 2; off >= 1; off >>= 1) ssum += __shfl_xor(ssum, off);
    float r = 1.0f / ssum;
#pragma unroll
    for (int i = 0; i < 8; ++i) acc[i] = ex[i] * r;
  }

  if constexpr (OUTHALF) {
    union { __half2 h[4]; uint4 u; } cv;
#pragma unroll
    for (int i = 0; i < 4; ++i)
      cv.h[i] = __floats2half2_rn(acc[2 * i], acc[2 * i + 1]);
    ((uint4*)out)[(size_t)node * LPG + lane] = cv.u;
  } else {
    float4* ov = (float4*)out;
    ov[(size_t)node * (F / 4) + lane * 2] =
        make_float4(acc[0], acc[1], acc[2], acc[3]);
    ov[(size_t)node * (F / 4) + lane * 2 + 1] =
        make_float4(acc[4], acc[5], acc[6], acc[7]);
  }
}

extern "C" void kernel_launch(void* const* d_in, const int* in_sizes, int n_in,
                              void* d_out, int out_size, void* d_ws, size_t ws_size,
                              hipStream_t stream) {
  const float* x  = (const float*)d_in[0];
  const float* W1 = (const float*)d_in[1];
  const float* b1 = (const float*)d_in[2];
  const float* W2 = (const float*)d_in[3];
  const float* b2 = (const float*)d_in[4];
  const int*   ei = (const int*)d_in[5];

  const int N = in_sizes[0] / 128;
  const int E = in_sizes[5] / 2;
  const int NB = (N + 255) >> BSHIFT;          // 391 for N=100K (<= NBPAD)
  const int SLICE = (E + NWG - 1) / NWG;
  const int* srcp = ei;
  const int* dstp = ei + E;

  auto align256 = [](size_t v) { return (v + 255) & ~(size_t)255; };
  char* ws = (char*)d_ws;
  size_t o_dinv   = 0;
  size_t o_rs     = align256(o_dinv + (size_t)N * 4);
  size_t o_cnts   = align256(o_rs + (size_t)(N + 1) * 4);
  size_t o_cur    = align256(o_cnts + (size_t)NWG * NBPAD * 4);
  size_t o_bstart = align256(o_cur + (size_t)NWG * NBPAD * 4);
  size_t o_wp1    = align256(o_bstart + (size_t)(NBPAD + 1) * 4);
  size_t o_wp2    = align256(o_wp1 + (size_t)128 * 128 * 2);
  size_t o_stg    = align256(o_wp2 + (size_t)128 * 64 * 2);
  size_t o_csr    = align256(o_stg + (size_t)E * 4);
  size_t o_pack   = align256(o_csr + (size_t)E * 4);
  size_t o_h1     = align256(o_pack + (size_t)E * 8);
  size_t o_s      = align256(o_h1 + (size_t)N * 128 * 2);

  float*    dinv     = (float*)(ws + o_dinv);
  int*      rowstart = (int*)(ws + o_rs);
  int*      counts   = (int*)(ws + o_cnts);
  int*      cur      = (int*)(ws + o_cur);
  int*      bstart   = (int*)(ws + o_bstart);
  _Float16* wp1      = (_Float16*)(ws + o_wp1);
  _Float16* wp2      = (_Float16*)(ws + o_wp2);
  unsigned* staging  = (unsigned*)(ws + o_stg);
  int*      csr_src  = (int*)(ws + o_csr);
  int2*     pack     = (int2*)(ws + o_pack);
  _Float16* h1       = (_Float16*)(ws + o_h1);  // [N,128] fp16; reused as h2 [N,64]
  _Float16* sbuf     = (_Float16*)(ws + o_s);   // [N,128] fp16 softmax output

  // CSR build — no global atomics anywhere
  wg_count<<<NWG, 256, 0, stream>>>(dstp, counts, E, NB, SLICE);
  scan_buckets<<<1, 1024, 0, stream>>>(counts, bstart, rowstart, NB, N, E);
  cell_scan<<<NB, 256, 0, stream>>>(counts, bstart, cur, NB);
  wg_scatter<<<NWG, 256, 0, stream>>>(srcp, dstp, cur, staging, E, NB, SLICE);
  bucket_finalize<<<NB, 256, 0, stream>>>(staging, bstart, csr_src, rowstart, dinv, N);
  make_pack<<<(E + 255) / 256, 256, 0, stream>>>(csr_src, dinv, pack, E);

  // Weight packing (tiny)
  pack_w<128><<<(128 * 128 + 255) / 256, 256, 0, stream>>>(W1, wp1);
  pack_w<64><<<(128 * 64 + 255) / 256, 256, 0, stream>>>(W2, wp2);

  // Layer 1
  gemm_mfma<128, false><<<(N + 63) / 64, 256, 0, stream>>>(x, wp1, h1, N);
  aggregate<128, true, true><<<(N + 15) / 16, 256, 0, stream>>>(
      (const __half*)h1, rowstart, pack, dinv, b1, sbuf, N);
  // Layer 2
  gemm_mfma<64, true><<<(N + 63) / 64, 256, 0, stream>>>(sbuf, wp2, h1, N);
  aggregate<64, false, false><<<(N + 31) / 32, 256, 0, stream>>>(
      (const __half*)h1, rowstart, pack, dinv, b2, d_out, N);
}